// Round 6
// baseline (442.894 us; speedup 1.0000x reference)
//
#include <hip/hip_runtime.h>

// Gather3d sparse-mode constants (from reference)
#define C_DIM 128
#define T_DIM 16
#define H_DIM 128
#define W_DIM 128
#define PAD_T 2
#define TT (T_DIM + PAD_T)           // 18 output planes per (n,c)

#define C_PER_WG   16                // channels per workgroup
#define C_PER_WAVE 4                 // channels per wave (4 waves/wg)

typedef float f4  __attribute__((ext_vector_type(4), aligned(16)));
typedef float f4u __attribute__((ext_vector_type(4), aligned(4)));  // 4B-aligned global load

// n-major decomposition: wg (chunk, n) writes out[n][16k:16k+16][:][:][:],
// each wave a contiguous 72KB run (4 channels x 18KB) -- write streams are
// sequential, matching the poison fill's 6.3 TB/s pattern. Reads gather
// 64B rows from x, served from per-XCD L2: grid.x = chunk -> XCD = chunk%8,
// so XCD k exclusively reads x[16k:16k+16) (16 MB partition; ~2MB hot
// working set < 4MB L2). Each x line is HBM-fetched once, reused 128x from
// L2. No LDS.
__global__ __launch_bounds__(256, 4) void gather3d_nmajor(
    const float* __restrict__ x,          // [C, T, H, W]
    const int*   __restrict__ active_idx, // [N, 2]
    float*       __restrict__ out,        // [N, C, TT, 16, 16]
    int N)
{
    const int chunk = blockIdx.x;         // 0..7  (fast dim -> XCD id)
    const int n     = blockIdx.y;
    const int tid   = threadIdx.x;
    const int wid   = tid >> 6;
    const int lane  = tid & 63;
    const int r     = lane >> 2;          // row in 16x16 block: 0..15
    const int q     = (lane & 3) << 2;    // col group start: 0,4,8,12

    // wg-uniform -> compiler scalarizes to s_load
    const int i0 = active_idx[2 * n];
    const int i1 = active_idx[2 * n + 1];

    const int c0 = chunk * C_PER_WG + wid * C_PER_WAVE;   // this wave's first c

    // Output: contiguous walk. Lane offsets r*16+q tile 0..255 -> each wave
    // store is 64 lanes x 16B = 1KB contiguous; walking (tt, c) keeps the
    // wave's whole 72KB stream sequential.
    float* op = out + ((size_t)n * C_DIM + c0) * (size_t)(TT * 256)
                    + r * 16 + q;

    // Input: x[c][t][i0 + r][i1 + q], misaligned-ok dwordx4 (gfx950 VMEM).
    const float* xp = x + (((size_t)c0 * T_DIM) * H_DIM + (size_t)(i0 + r)) * W_DIM
                        + i1 + q;

    const f4 z = {0.f, 0.f, 0.f, 0.f};

    for (int cc = 0; cc < C_PER_WAVE; ++cc) {
        // tt = 0,1: causal time padding -> zero planes
        *(f4*)op = z;  op += 256;
        *(f4*)op = z;  op += 256;
        // tt = 2..17 -> t = 0..15: 16 independent load->store chains,
        // fully unrolled for MLP (hides L2-hit latency ~200cyc).
        #pragma unroll
        for (int t = 0; t < T_DIM; ++t) {
            f4 v = *(const f4u*)(xp + (size_t)t * (H_DIM * W_DIM));
            *(f4*)op = v;
            op += 256;
        }
        xp += (size_t)T_DIM * H_DIM * W_DIM;   // next channel
    }
}

extern "C" void kernel_launch(void* const* d_in, const int* in_sizes, int n_in,
                              void* d_out, int out_size, void* d_ws, size_t ws_size,
                              hipStream_t stream) {
    const float* x   = (const float*)d_in[0];
    const int*   idx = (const int*)d_in[1];
    float*       out = (float*)d_out;

    const int N = in_sizes[1] / 2;   // 128 active indices

    dim3 grid(C_DIM / C_PER_WG, N);  // chunk fast (-> XCD partition), n slow
    gather3d_nmajor<<<grid, dim3(256), 0, stream>>>(x, idx, out, N);
}